// Round 4
// baseline (233.913 us; speedup 1.0000x reference)
//
#include <hip/hip_runtime.h>
#include <hip/hip_bf16.h>

typedef __attribute__((ext_vector_type(8))) short bf16x8;
typedef __attribute__((ext_vector_type(4))) float f32x4;

#define NB 16
#define C 256
#define HH 56
#define WW 56
#define HW 3136
#define CHW 802816
#define NPIX 50176
#define PH 58
#define PW 58
#define KTOT 2304
#define PPI 3364      // 58*58 padded pixels per image
#define NPIXP 53824   // 16*3364 total padded pixels

#define GLL(g, l) __builtin_amdgcn_global_load_lds( \
    (const __attribute__((address_space(1))) void*)(g), \
    (__attribute__((address_space(3))) void*)(l), 16, 0, 0)

// ---- kernel 1 (merged): BN stats + weight prep + Tp border zero + csum zero ----
// blocks 0..255: stats (fp64 accum, float4 loads); 256..319: weight transform into
// MFMA-FRAGMENT order (4 co per block); 320..433: Tp border zero; 434..486: csum zero.
// Wp fragment layout (shorts): idx = (((ck*9+tap)*16)+cb)*512 + (quad*16+row16)*8 + j
//   holds bf16(w[co=cb*16+row16][c][tap]) where perm-slot p=(c&31)*8+(c>>5),
//   ck=p>>5, quad=(p&31)>>3, j=p&7.  One dwordx4/lane = the exact a-frag.
__global__ __launch_bounds__(1024) void prep_stats_kernel(const float* __restrict__ x,
                             const float* __restrict__ gamma, const float* __restrict__ cw,
                             double* __restrict__ stats, unsigned short* __restrict__ Wp,
                             unsigned short* __restrict__ Tp, float* __restrict__ csum) {
  int b = blockIdx.x, tid = threadIdx.x;
  if (b < 256) {
    int c = b;
    double s = 0.0, s2 = 0.0;
    const float* xc = x + (size_t)c * HW;
    for (int k = tid; k < NB * (HW / 4); k += 1024) {   // 12544 float4s
      int n = k / (HW / 4), i = k - n * (HW / 4);
      float4 v = *(const float4*)(xc + (size_t)n * CHW + i * 4);
      double a = v.x, bb = v.y, cc = v.z, d = v.w;
      s  += (a + bb) + (cc + d);
      s2 += (a * a + bb * bb) + (cc * cc + d * d);
    }
    __shared__ double rs[1024], rq[1024];
    rs[tid] = s; rq[tid] = s2; __syncthreads();
    for (int o = 512; o > 0; o >>= 1) {
      if (tid < o) { rs[tid] += rs[tid + o]; rq[tid] += rq[tid + o]; }
      __syncthreads();
    }
    if (tid == 0) {
      double mean = rs[0] / (double)NPIX;
      double var = rq[0] / (double)NPIX - mean * mean;
      stats[c] = mean;
      stats[C + c] = (double)gamma[c] / sqrt(var + 1e-4);
    }
  } else if (b < 320) {
    // weight transform; 4 co per block, coalesced 9-float reads per thread
    int co = (b - 256) * 4 + (tid >> 8);
    int c  = tid & 255;
    const float* src = cw + (size_t)co * KTOT + c * 9;
    int p = (c & 31) * 8 + (c >> 5);           // perm slot for channel c
    int ck = p >> 5, v = p & 31;
    int quad = v >> 3, j = v & 7;
    int cb = co >> 4, row16 = co & 15;
    int lane8 = (quad * 16 + row16) * 8 + j;
#pragma unroll
    for (int tap = 0; tap < 9; ++tap) {
      unsigned u = __builtin_bit_cast(unsigned, src[tap]);
      unsigned lsb = (u >> 16) & 1u;
      u += 0x7FFFu + lsb;
      Wp[(size_t)(((ck * 9 + tap) * 16) + cb) * 512 + lane8] = (unsigned short)(u >> 16);
    }
  } else if (b < 434) {
    int g = (b - 320) * 1024 + tid;  // 114*1024 = 116736 = 16*228*32 exactly
    int n = g / 7296; int r = g - n * 7296;
    int pix = r >> 5, c8 = r & 31;
    int h, w;
    if (pix < 58)      { h = 0;  w = pix; }
    else if (pix < 116){ h = 57; w = pix - 58; }
    else { int rem = pix - 116; h = 1 + (rem >> 1); w = (rem & 1) ? 57 : 0; }
    uint4 z = {0u, 0u, 0u, 0u};
    *(uint4*)(Tp + (size_t)((n * PH + h) * PW + w) * C + c8 * 8) = z;
  } else {
    int i = (b - 434) * 1024 + tid;
    if (i < NPIXP) csum[i] = 0.f;
  }
}

// ------- kernel 2: ternarize -> padded NHWC (channel-permuted) bf16 Tp + c_sum -------
// channel permutation: slot p = (c&31)*8 + (c>>5)  <->  c = (p&7)*32 + (p>>3)
__global__ __launch_bounds__(256) void ternarize_kernel(const float* __restrict__ x,
                                 const float* __restrict__ beta,
                                 const double* __restrict__ stats,
                                 unsigned short* __restrict__ Tp, float* __restrict__ csum) {
  int bid = blockIdx.x, tid = threadIdx.x;
  int n = bid / HH, h = bid - n * HH;
  __shared__ float xs[256][57];   // stride 57: transposed reads conflict-free
  const float* xb = x + (size_t)n * CHW + h * WW;
#pragma unroll
  for (int j = 0; j < 14; ++j) {
    int idx = j * 256 + tid;
    int c = idx / 14, q = idx - c * 14;
    float4 v = *(const float4*)(xb + (size_t)c * HW + q * 4);
    float* row = &xs[c][q * 4];
    row[0] = v.x; row[1] = v.y; row[2] = v.z; row[3] = v.w;
  }
  int c8 = tid & 31;
  double mu[8], sc[8], bt[8];
#pragma unroll
  for (int e = 0; e < 8; ++e) {
    int c = c8 + 32 * e;
    mu[e] = stats[c]; sc[e] = stats[C + c]; bt[e] = (double)beta[c];
  }
  __syncthreads();
  unsigned short* tb = Tp + ((size_t)(n * PH + h + 1) * PW + 1) * C;
  float* cs = csum + (size_t)(n * PH + h + 1) * PW + 1;
#pragma unroll
  for (int p = 0; p < 7; ++p) {
    int idx = p * 256 + tid;
    int w = idx >> 5;
    unsigned bits[4];
    float msum = 0.f;
#pragma unroll
    for (int e2 = 0; e2 < 4; ++e2) {
      unsigned lo, hi;
      {
        double xn = ((double)xs[c8 + 64 * e2][w] - mu[2 * e2]) * sc[2 * e2] + bt[2 * e2];
        lo = (xn > 0.0) ? 0x3F80u : 0xBF80u;
        msum += (float)fmin(fabs(xn), 1.0);
      }
      {
        double xn = ((double)xs[c8 + 64 * e2 + 32][w] - mu[2 * e2 + 1]) * sc[2 * e2 + 1] + bt[2 * e2 + 1];
        hi = (xn > 0.0) ? 0x3F80u : 0xBF80u;
        msum += (float)fmin(fabs(xn), 1.0);
      }
      bits[e2] = lo | (hi << 16);
    }
    msum += __shfl_xor(msum, 1); msum += __shfl_xor(msum, 2);
    msum += __shfl_xor(msum, 4); msum += __shfl_xor(msum, 8);
    msum += __shfl_xor(msum, 16);
    uint4 v4; v4.x = bits[0]; v4.y = bits[1]; v4.z = bits[2]; v4.w = bits[3];
    *(uint4*)(tb + (size_t)w * C + c8 * 8) = v4;
    if (c8 == 0) cs[w] = msum;
  }
}

// ------- kernel 3: A-in-registers union-window implicit-GEMM ternary conv -------
// Tile: M=64 co x N=256 padded pixels, 256 thr (4 waves). 8 K-chunks of 32 ch.
// A-fragments load DIRECTLY global->VGPR from fragment-ordered Wp (one coalesced
// dwordx4 per (tap,mi); L1/L2-hot, 1.18 MB resident) -- A no longer touches LDS.
// LDS = B double-buffer only: 2 x 384rows x 32ch = 49,152 B -> 2 blocks/CU:
// anti-phased blocks (R1's proven cover) PLUS true B prefetch (GLL for chunk s+1
// issued at chunk-s start, a full compute phase in flight before its drain).
// LDS-read traffic halves to 0.25 b128/MFMA (17.7 us floor) -> MFMA-bound (28.5 us).
// B XOR-on-global-segment swizzle unchanged (0 conflicts measured).
__global__ __launch_bounds__(256, 2) void conv_kernel(const unsigned short* __restrict__ Wp,
    const unsigned short* __restrict__ Tp, const float* __restrict__ convb,
    const float* __restrict__ csum, const float* __restrict__ betab,
    float* __restrict__ out) {
  int bid = blockIdx.x;
  int ptg = bid >> 5, xcd = bid & 7, ct = (bid >> 3) & 3;
  int pt = ptg * 8 + xcd;                    // pixel tile (same-XCD blocks share it)
  if (pt >= 211) return;
  int tid = threadIdx.x;

  __shared__ __align__(16) unsigned short Bs[2][384 * 32];      // 2 x 24576 B

  // ---- B staging plan: 6 GLL rounds over union window [pt*256-59, +384)
  int wstart = pt * 256 - 59;
  int bofs[6];
#pragma unroll
  for (int r = 0; r < 6; ++r) {
    int lin = r * 256 + tid;
    int bpix = lin >> 2, pseg = lin & 3;
    int lseg = pseg ^ ((bpix >> 1) & 3);
    int q = wstart + bpix;
    q = q < 0 ? 0 : (q >= NPIXP ? NPIXP - 1 : q);   // clamped rows feed only skipped outputs
    bofs[r] = q * C + lseg * 8;
  }

  int lane = tid & 63, wid = tid >> 6;
  int quad = lane >> 4, row16 = lane & 15;
  int pixb = wid * 64 + row16;                 // staged row = pixb + ni*16 + kh*58 + kw

  // A fragment pointer: element (bf16x8) index = (((ck*9+tap)*16)+cb)*64 + lane
  const bf16x8* Ab = (const bf16x8*)Wp + lane;
  int cb0 = ct * 4;                            // cb = cb0 + mi

  f32x4 acc[4][4];
#pragma unroll
  for (int mi = 0; mi < 4; ++mi)
#pragma unroll
    for (int ni = 0; ni < 4; ++ni)
      acc[mi][ni] = (f32x4){0.f, 0.f, 0.f, 0.f};

  // prologue: stage B chunk 0 into buffer 0
#pragma unroll
  for (int r = 0; r < 6; ++r) GLL(Tp + bofs[r], &Bs[0][(r * 256 + tid) * 8]);

  for (int ck = 0; ck < 8; ++ck) {
    int cur = ck & 1;
    __syncthreads();           // drains B(ck) prefetch (in flight a full chunk)
    if (ck < 7) {
      int c2 = (ck + 1) * 32;
#pragma unroll
      for (int r = 0; r < 6; ++r) GLL(Tp + bofs[r] + c2, &Bs[cur ^ 1][(r * 256 + tid) * 8]);
    }
    const unsigned short* bB = &Bs[cur][0];
    __builtin_amdgcn_s_setprio(1);
#pragma unroll
    for (int kh = 0; kh < 3; ++kh) {
      bf16x8 a[3][4];
#pragma unroll
      for (int kw = 0; kw < 3; ++kw)
#pragma unroll
        for (int mi = 0; mi < 4; ++mi)
          a[kw][mi] = Ab[(size_t)(((ck * 9 + kh * 3 + kw) * 16) + cb0 + mi) * 64];
#pragma unroll
      for (int kw = 0; kw < 3; ++kw) {
        bf16x8 b[4];
#pragma unroll
        for (int ni = 0; ni < 4; ++ni) {
          int pix = pixb + ni * 16 + kh * 58 + kw;
          b[ni] = *(const bf16x8*)(bB + pix * 32 + ((quad ^ ((pix >> 1) & 3)) * 8));
        }
#pragma unroll
        for (int mi = 0; mi < 4; ++mi)
#pragma unroll
          for (int ni = 0; ni < 4; ++ni)
            acc[mi][ni] = __builtin_amdgcn_mfma_f32_16x16x32_bf16(a[kw][mi], b[ni], acc[mi][ni], 0, 0, 0);
      }
    }
    __builtin_amdgcn_s_setprio(0);
  }

  // epilogue: out = (acc + conv_b) * beta_map(inline) ; skip padded-border outputs
  int co0 = ct * 64;
  float bb = betab[0];
#pragma unroll
  for (int ni = 0; ni < 4; ++ni) {
    int pp = pt * 256 + wid * 64 + ni * 16 + row16;
    if (pp >= NPIXP) continue;
    int n = pp / PPI; int r2 = pp - n * PPI;
    int ph = r2 / PW;  int pw = r2 - ph * PW;
    if (ph < 1 || ph > 56 || pw < 1 || pw > 56) continue;
    const float* cp = csum + (size_t)(n * PH + ph - 1) * PW + (pw - 1);
    float s9 = 0.f;
#pragma unroll
    for (int i = 0; i < 3; ++i)
#pragma unroll
      for (int j = 0; j < 3; ++j) s9 += cp[i * PW + j];
    int rows = 3 - (ph == 1) - (ph == 56);
    int cols = 3 - (pw == 1) - (pw == 56);
    float bm = (s9 + bb) / (256.0f * (float)(rows * cols) + bb);
    int pix = (ph - 1) * WW + (pw - 1);
    float* ob = out + (size_t)n * CHW + pix;
#pragma unroll
    for (int mi = 0; mi < 4; ++mi) {
      int co = co0 + mi * 16 + quad * 4;
#pragma unroll
      for (int rg = 0; rg < 4; ++rg) {
        ob[(size_t)(co + rg) * HW] = (acc[mi][ni][rg] + convb[co + rg]) * bm;
      }
    }
  }
}

extern "C" void kernel_launch(void* const* d_in, const int* in_sizes, int n_in,
                              void* d_out, int out_size, void* d_ws, size_t ws_size,
                              hipStream_t stream) {
  const float* x     = (const float*)d_in[0];
  const float* gamma = (const float*)d_in[1];
  const float* beta  = (const float*)d_in[2];
  const float* convw = (const float*)d_in[3];
  const float* convb = (const float*)d_in[4];
  const float* betab = (const float*)d_in[5];
  float* out = (float*)d_out;

  char* ws = (char*)d_ws;
  unsigned short* Tp   = (unsigned short*)(ws);                 // 16*58*58*256*2 = 27,557,888
  unsigned short* Wp   = (unsigned short*)(ws + 27557888);      // 256*2304*2     =  1,179,648
  float*          csum = (float*)(ws + 28737536);               // 16*58*58*4     =    215,296
  double*         stats= (double*)(ws + 29153536);              // 512*8          =      4,096

  prep_stats_kernel<<<487, 1024, 0, stream>>>(x, gamma, convw, stats, Wp, Tp, csum);
  ternarize_kernel<<<896, 256, 0, stream>>>(x, beta, stats, Tp, csum);
  conv_kernel<<<864, 256, 0, stream>>>(Wp, Tp, convb, csum, betab, out);
}

// Round 5
// 201.860 us; speedup vs baseline: 1.1588x; 1.1588x over previous
//
#include <hip/hip_runtime.h>
#include <hip/hip_bf16.h>

typedef __attribute__((ext_vector_type(8))) short bf16x8;
typedef __attribute__((ext_vector_type(4))) float f32x4;

#define NB 16
#define C 256
#define HH 56
#define WW 56
#define HW 3136
#define CHW 802816
#define NPIX 50176
#define PH 58
#define PW 58
#define KTOT 2304
#define PPI 3364      // 58*58 padded pixels per image
#define NPIXP 53824   // 16*3364 total padded pixels

#define GLL(g, l) __builtin_amdgcn_global_load_lds( \
    (const __attribute__((address_space(1))) void*)(g), \
    (__attribute__((address_space(3))) void*)(l), 16, 0, 0)

// ---- kernel 1 (merged): BN stats + weight prep + Tp border zero + csum zero ----
// blocks 0..255: stats (fp64 accum, float4 loads); 256..319: weight transform into
// MFMA-FRAGMENT order (4 co per block); 320..433: Tp border zero; 434..486: csum zero.
// Wp fragment layout (shorts): idx = (((ck*9+tap)*16)+cb)*512 + (quad*16+row16)*8 + j
//   holds bf16(w[co=cb*16+row16][c][tap]) where perm-slot p=(c&31)*8+(c>>5),
//   ck=p>>5, quad=(p&31)>>3, j=p&7.  One dwordx4/lane = the exact a-frag.
//   (layout hardware-verified in round 4: bit-identical output)
__global__ __launch_bounds__(1024) void prep_stats_kernel(const float* __restrict__ x,
                             const float* __restrict__ gamma, const float* __restrict__ cw,
                             double* __restrict__ stats, unsigned short* __restrict__ Wp,
                             unsigned short* __restrict__ Tp, float* __restrict__ csum) {
  int b = blockIdx.x, tid = threadIdx.x;
  if (b < 256) {
    int c = b;
    double s = 0.0, s2 = 0.0;
    const float* xc = x + (size_t)c * HW;
    for (int k = tid; k < NB * (HW / 4); k += 1024) {   // 12544 float4s
      int n = k / (HW / 4), i = k - n * (HW / 4);
      float4 v = *(const float4*)(xc + (size_t)n * CHW + i * 4);
      double a = v.x, bb = v.y, cc = v.z, d = v.w;
      s  += (a + bb) + (cc + d);
      s2 += (a * a + bb * bb) + (cc * cc + d * d);
    }
    __shared__ double rs[1024], rq[1024];
    rs[tid] = s; rq[tid] = s2; __syncthreads();
    for (int o = 512; o > 0; o >>= 1) {
      if (tid < o) { rs[tid] += rs[tid + o]; rq[tid] += rq[tid + o]; }
      __syncthreads();
    }
    if (tid == 0) {
      double mean = rs[0] / (double)NPIX;
      double var = rq[0] / (double)NPIX - mean * mean;
      stats[c] = mean;
      stats[C + c] = (double)gamma[c] / sqrt(var + 1e-4);
    }
  } else if (b < 320) {
    // weight transform; 4 co per block, coalesced 9-float reads per thread
    int co = (b - 256) * 4 + (tid >> 8);
    int c  = tid & 255;
    const float* src = cw + (size_t)co * KTOT + c * 9;
    int p = (c & 31) * 8 + (c >> 5);           // perm slot for channel c
    int ck = p >> 5, v = p & 31;
    int quad = v >> 3, j = v & 7;
    int cb = co >> 4, row16 = co & 15;
    int lane8 = (quad * 16 + row16) * 8 + j;
#pragma unroll
    for (int tap = 0; tap < 9; ++tap) {
      unsigned u = __builtin_bit_cast(unsigned, src[tap]);
      unsigned lsb = (u >> 16) & 1u;
      u += 0x7FFFu + lsb;
      Wp[(size_t)(((ck * 9 + tap) * 16) + cb) * 512 + lane8] = (unsigned short)(u >> 16);
    }
  } else if (b < 434) {
    int g = (b - 320) * 1024 + tid;  // 114*1024 = 116736 = 16*228*32 exactly
    int n = g / 7296; int r = g - n * 7296;
    int pix = r >> 5, c8 = r & 31;
    int h, w;
    if (pix < 58)      { h = 0;  w = pix; }
    else if (pix < 116){ h = 57; w = pix - 58; }
    else { int rem = pix - 116; h = 1 + (rem >> 1); w = (rem & 1) ? 57 : 0; }
    uint4 z = {0u, 0u, 0u, 0u};
    *(uint4*)(Tp + (size_t)((n * PH + h) * PW + w) * C + c8 * 8) = z;
  } else {
    int i = (b - 434) * 1024 + tid;
    if (i < NPIXP) csum[i] = 0.f;
  }
}

// ------- kernel 2: ternarize -> padded NHWC (channel-permuted) bf16 Tp + c_sum -------
// channel permutation: slot p = (c&31)*8 + (c>>5)  <->  c = (p&7)*32 + (p>>3)
__global__ __launch_bounds__(256) void ternarize_kernel(const float* __restrict__ x,
                                 const float* __restrict__ beta,
                                 const double* __restrict__ stats,
                                 unsigned short* __restrict__ Tp, float* __restrict__ csum) {
  int bid = blockIdx.x, tid = threadIdx.x;
  int n = bid / HH, h = bid - n * HH;
  __shared__ float xs[256][57];   // stride 57: transposed reads conflict-free
  const float* xb = x + (size_t)n * CHW + h * WW;
#pragma unroll
  for (int j = 0; j < 14; ++j) {
    int idx = j * 256 + tid;
    int c = idx / 14, q = idx - c * 14;
    float4 v = *(const float4*)(xb + (size_t)c * HW + q * 4);
    float* row = &xs[c][q * 4];
    row[0] = v.x; row[1] = v.y; row[2] = v.z; row[3] = v.w;
  }
  int c8 = tid & 31;
  double mu[8], sc[8], bt[8];
#pragma unroll
  for (int e = 0; e < 8; ++e) {
    int c = c8 + 32 * e;
    mu[e] = stats[c]; sc[e] = stats[C + c]; bt[e] = (double)beta[c];
  }
  __syncthreads();
  unsigned short* tb = Tp + ((size_t)(n * PH + h + 1) * PW + 1) * C;
  float* cs = csum + (size_t)(n * PH + h + 1) * PW + 1;
#pragma unroll
  for (int p = 0; p < 7; ++p) {
    int idx = p * 256 + tid;
    int w = idx >> 5;
    unsigned bits[4];
    float msum = 0.f;
#pragma unroll
    for (int e2 = 0; e2 < 4; ++e2) {
      unsigned lo, hi;
      {
        double xn = ((double)xs[c8 + 64 * e2][w] - mu[2 * e2]) * sc[2 * e2] + bt[2 * e2];
        lo = (xn > 0.0) ? 0x3F80u : 0xBF80u;
        msum += (float)fmin(fabs(xn), 1.0);
      }
      {
        double xn = ((double)xs[c8 + 64 * e2 + 32][w] - mu[2 * e2 + 1]) * sc[2 * e2 + 1] + bt[2 * e2 + 1];
        hi = (xn > 0.0) ? 0x3F80u : 0xBF80u;
        msum += (float)fmin(fabs(xn), 1.0);
      }
      bits[e2] = lo | (hi << 16);
    }
    msum += __shfl_xor(msum, 1); msum += __shfl_xor(msum, 2);
    msum += __shfl_xor(msum, 4); msum += __shfl_xor(msum, 8);
    msum += __shfl_xor(msum, 16);
    uint4 v4; v4.x = bits[0]; v4.y = bits[1]; v4.z = bits[2]; v4.w = bits[3];
    *(uint4*)(tb + (size_t)w * C + c8 * 8) = v4;
    if (c8 == 0) cs[w] = msum;
  }
}

// ------- kernel 3: A-in-VGPR (reg-dbuf) kh-split implicit-GEMM ternary conv -------
// Tile: M=64 co x N=256 pix, 256 thr (4 waves), 24 stages (kh-major, c-chunk of 32).
// A-fragments: double-buffered in REGISTERS, loaded global->VGPR from the
// fragment-ordered Wp (12 coalesced dwordx4/stage, L1-hot: all 4 waves read the
// same 12 KB slice). A(s+1) loads + B(s+1) GLLs are issued together at stage-s
// top; the next stage's __syncthreads vmcnt(0) drains both after a FULL compute
// phase in flight (vmcnt in-order retirement now harmless: nothing waits mid-phase,
// and compute(s) starts on already-resident a_cur with zero waits).
// LDS = B double-buffer only: 2 x 320 x 32 = 40,960 B. LDS-read traffic halves
// to 12 b128/stage (~19 us chip) -> under the 25 us MFMA floor => MFMA-bound.
// All GLL offsets hoisted (bofs3[3][5] precomputed once) -- fixes R3's VALU bloat.
// Stage loop unrolled x2 for static a_cur/a_next register binding (no scratch).
__global__ __launch_bounds__(256, 2) void conv_kernel(const unsigned short* __restrict__ Wp,
    const unsigned short* __restrict__ Tp, const float* __restrict__ convb,
    const float* __restrict__ csum, const float* __restrict__ betab,
    float* __restrict__ out) {
  int bid = blockIdx.x;
  int ptg = bid >> 5, xcd = bid & 7, ct = (bid >> 3) & 3;
  int pt = ptg * 8 + xcd;                    // pixel tile (same-XCD blocks share it)
  if (pt >= 211) return;
  int tid = threadIdx.x;

  __shared__ __align__(16) unsigned short Bs[2][320 * 32];   // 2 x 20480 B

  // ---- B staging plan: 5 GLL rounds; offsets fully precomputed per kh (15 ints)
  int bofs3[3][5];
#pragma unroll
  for (int r = 0; r < 5; ++r) {
    int lin = r * 256 + tid;
    int bpix = lin >> 2;
    int bl = (lin & 3) ^ ((bpix >> 1) & 3);
#pragma unroll
    for (int kh = 0; kh < 3; ++kh) {
      int q = pt * 256 + (kh - 1) * 58 - 32 + bpix;
      q = q < 0 ? 0 : (q >= NPIXP ? NPIXP - 1 : q);  // clamped rows feed only skipped outputs
      bofs3[kh][r] = q * C + bl * 8;
    }
  }

  int lane = tid & 63, wid = tid >> 6;
  int quad = lane >> 4, row16 = lane & 15;
  int jbase = wid * 64 + row16 + 31;           // + ni*16 + kw -> staged B row
  const bf16x8* Ab = (const bf16x8*)Wp + lane; // lane's fragment slot
  int cb0 = ct * 4;                            // co-block base (cb = cb0 + mi)

  f32x4 acc[4][4];
#pragma unroll
  for (int mi = 0; mi < 4; ++mi)
#pragma unroll
    for (int ni = 0; ni < 4; ++ni)
      acc[mi][ni] = (f32x4){0.f, 0.f, 0.f, 0.f};

  bf16x8 aA[12], aB[12];   // A-fragment register double-buffer

  // prologue: stage B(0) + load A(0) (stage 0: kh=0, ck=0 -> frag base cb0*64)
#pragma unroll
  for (int r = 0; r < 5; ++r) GLL(Tp + bofs3[0][r], &Bs[0][(r * 256 + tid) * 8]);
#pragma unroll
  for (int t3 = 0; t3 < 3; ++t3)
#pragma unroll
    for (int mi = 0; mi < 4; ++mi)
      aA[t3 * 4 + mi] = Ab[(cb0 + t3 * 16 + mi) * 64];

#define STAGE(S, ACUR, ANEXT, PREF)                                              \
  {                                                                              \
    __syncthreads();  /* drains B(S)+A(S+?) prefetch (one full phase old) */     \
    if (PREF) {                                                                  \
      int s2 = (S) + 1; int kh2 = s2 >> 3; int c2 = (s2 & 7) * 32;               \
      _Pragma("unroll")                                                          \
      for (int r = 0; r < 5; ++r)                                                \
        GLL(Tp + bofs3[kh2][r] + c2, &Bs[s2 & 1][(r * 256 + tid) * 8]);          \
      int fb = (((s2 & 7) * 9 + kh2 * 3) * 16 + cb0) * 64;                       \
      _Pragma("unroll")                                                          \
      for (int t3 = 0; t3 < 3; ++t3)                                             \
        _Pragma("unroll")                                                        \
        for (int mi = 0; mi < 4; ++mi)                                           \
          ANEXT[t3 * 4 + mi] = Ab[fb + (t3 * 16 + mi) * 64];                     \
    }                                                                            \
    const unsigned short* bB = &Bs[(S) & 1][0];                                  \
    __builtin_amdgcn_s_setprio(1);                                               \
    _Pragma("unroll")                                                            \
    for (int kw = 0; kw < 3; ++kw) {                                             \
      bf16x8 bfr[4];                                                             \
      _Pragma("unroll")                                                          \
      for (int ni = 0; ni < 4; ++ni) {                                           \
        int pix = jbase + ni * 16 + kw;                                          \
        bfr[ni] = *(const bf16x8*)(bB + pix * 32 + ((quad ^ ((pix >> 1) & 3)) * 8)); \
      }                                                                          \
      _Pragma("unroll")                                                          \
      for (int mi = 0; mi < 4; ++mi)                                             \
        _Pragma("unroll")                                                        \
        for (int ni = 0; ni < 4; ++ni)                                           \
          acc[mi][ni] = __builtin_amdgcn_mfma_f32_16x16x32_bf16(                 \
              ACUR[kw * 4 + mi], bfr[ni], acc[mi][ni], 0, 0, 0);                 \
    }                                                                            \
    __builtin_amdgcn_s_setprio(0);                                               \
  }

  for (int sp = 0; sp < 12; ++sp) {
    int s0 = 2 * sp;
    STAGE(s0, aA, aB, 1);
    STAGE(s0 + 1, aB, aA, (sp < 11));
  }
#undef STAGE

  // epilogue: out = (acc + conv_b) * beta_map(inline) ; skip padded-border outputs
  int co0 = ct * 64;
  float bb = betab[0];
#pragma unroll
  for (int ni = 0; ni < 4; ++ni) {
    int pp = pt * 256 + wid * 64 + ni * 16 + row16;
    if (pp >= NPIXP) continue;
    int n = pp / PPI; int r2 = pp - n * PPI;
    int ph = r2 / PW;  int pw = r2 - ph * PW;
    if (ph < 1 || ph > 56 || pw < 1 || pw > 56) continue;
    const float* cp = csum + (size_t)(n * PH + ph - 1) * PW + (pw - 1);
    float s9 = 0.f;
#pragma unroll
    for (int i = 0; i < 3; ++i)
#pragma unroll
      for (int j = 0; j < 3; ++j) s9 += cp[i * PW + j];
    int rows = 3 - (ph == 1) - (ph == 56);
    int cols = 3 - (pw == 1) - (pw == 56);
    float bm = (s9 + bb) / (256.0f * (float)(rows * cols) + bb);
    int pix = (ph - 1) * WW + (pw - 1);
    float* ob = out + (size_t)n * CHW + pix;
#pragma unroll
    for (int mi = 0; mi < 4; ++mi) {
      int co = co0 + mi * 16 + quad * 4;
#pragma unroll
      for (int rg = 0; rg < 4; ++rg) {
        ob[(size_t)(co + rg) * HW] = (acc[mi][ni][rg] + convb[co + rg]) * bm;
      }
    }
  }
}

extern "C" void kernel_launch(void* const* d_in, const int* in_sizes, int n_in,
                              void* d_out, int out_size, void* d_ws, size_t ws_size,
                              hipStream_t stream) {
  const float* x     = (const float*)d_in[0];
  const float* gamma = (const float*)d_in[1];
  const float* beta  = (const float*)d_in[2];
  const float* convw = (const float*)d_in[3];
  const float* convb = (const float*)d_in[4];
  const float* betab = (const float*)d_in[5];
  float* out = (float*)d_out;

  char* ws = (char*)d_ws;
  unsigned short* Tp   = (unsigned short*)(ws);                 // 16*58*58*256*2 = 27,557,888
  unsigned short* Wp   = (unsigned short*)(ws + 27557888);      // 256*2304*2     =  1,179,648
  float*          csum = (float*)(ws + 28737536);               // 16*58*58*4     =    215,296
  double*         stats= (double*)(ws + 29153536);              // 512*8          =      4,096

  prep_stats_kernel<<<487, 1024, 0, stream>>>(x, gamma, convw, stats, Wp, Tp, csum);
  ternarize_kernel<<<896, 256, 0, stream>>>(x, beta, stats, Tp, csum);
  conv_kernel<<<864, 256, 0, stream>>>(Wp, Tp, convb, csum, betab, out);
}

// Round 6
// 197.523 us; speedup vs baseline: 1.1842x; 1.0220x over previous
//
#include <hip/hip_runtime.h>
#include <hip/hip_bf16.h>

typedef __attribute__((ext_vector_type(8))) short bf16x8;
typedef __attribute__((ext_vector_type(4))) float f32x4;

#define NB 16
#define C 256
#define HH 56
#define WW 56
#define HW 3136
#define CHW 802816
#define NPIX 50176
#define PH 58
#define PW 58
#define KTOT 2304
#define PPI 3364      // 58*58 padded pixels per image
#define NPIXP 53824   // 16*3364 total padded pixels

#define GLL(g, l) __builtin_amdgcn_global_load_lds( \
    (const __attribute__((address_space(1))) void*)(g), \
    (__attribute__((address_space(3))) void*)(l), 16, 0, 0)

// ---- kernel 1 (merged): BN stats + weight prep + Tp border zero + csum zero ----
// blocks 0..255: stats (fp64 accum, float4 loads); 256..319: weight transform
// OIHW -> [co][tap][perm(c)] (flat layout, verified R0-R3); 320..433: Tp border
// zero; 434..486: csum zero.
__global__ __launch_bounds__(1024) void prep_stats_kernel(const float* __restrict__ x,
                             const float* __restrict__ gamma, const float* __restrict__ cw,
                             double* __restrict__ stats, unsigned short* __restrict__ Wp,
                             unsigned short* __restrict__ Tp, float* __restrict__ csum) {
  int b = blockIdx.x, tid = threadIdx.x;
  if (b < 256) {
    int c = b;
    double s = 0.0, s2 = 0.0;
    const float* xc = x + (size_t)c * HW;
    for (int k = tid; k < NB * (HW / 4); k += 1024) {   // 12544 float4s
      int n = k / (HW / 4), i = k - n * (HW / 4);
      float4 v = *(const float4*)(xc + (size_t)n * CHW + i * 4);
      double a = v.x, bb = v.y, cc = v.z, d = v.w;
      s  += (a + bb) + (cc + d);
      s2 += (a * a + bb * bb) + (cc * cc + d * d);
    }
    __shared__ double rs[1024], rq[1024];
    rs[tid] = s; rq[tid] = s2; __syncthreads();
    for (int o = 512; o > 0; o >>= 1) {
      if (tid < o) { rs[tid] += rs[tid + o]; rq[tid] += rq[tid + o]; }
      __syncthreads();
    }
    if (tid == 0) {
      double mean = rs[0] / (double)NPIX;
      double var = rq[0] / (double)NPIX - mean * mean;
      stats[c] = mean;
      stats[C + c] = (double)gamma[c] / sqrt(var + 1e-4);
    }
  } else if (b < 320) {
    // weights OIHW -> [co][tap][perm(c)] bf16 (RNE); 4 co per block, coalesced reads
    int co = (b - 256) * 4 + (tid >> 8);
    int c  = tid & 255;
    const float* src = cw + (size_t)co * KTOT + c * 9;
    unsigned short* dst = Wp + (size_t)co * KTOT;
    int p = (c & 31) * 8 + (c >> 5);           // perm slot for channel c
#pragma unroll
    for (int t9 = 0; t9 < 9; ++t9) {
      unsigned u = __builtin_bit_cast(unsigned, src[t9]);
      unsigned lsb = (u >> 16) & 1u;
      u += 0x7FFFu + lsb;
      dst[t9 * 256 + p] = (unsigned short)(u >> 16);
    }
  } else if (b < 434) {
    int g = (b - 320) * 1024 + tid;  // 114*1024 = 116736 = 16*228*32 exactly
    int n = g / 7296; int r = g - n * 7296;
    int pix = r >> 5, c8 = r & 31;
    int h, w;
    if (pix < 58)      { h = 0;  w = pix; }
    else if (pix < 116){ h = 57; w = pix - 58; }
    else { int rem = pix - 116; h = 1 + (rem >> 1); w = (rem & 1) ? 57 : 0; }
    uint4 z = {0u, 0u, 0u, 0u};
    *(uint4*)(Tp + (size_t)((n * PH + h) * PW + w) * C + c8 * 8) = z;
  } else {
    int i = (b - 434) * 1024 + tid;
    if (i < NPIXP) csum[i] = 0.f;
  }
}

// ------- kernel 2: ternarize -> padded NHWC (channel-permuted) bf16 Tp + c_sum -------
// channel permutation: slot p = (c&31)*8 + (c>>5)  <->  c = (p&7)*32 + (p>>3)
__global__ __launch_bounds__(256) void ternarize_kernel(const float* __restrict__ x,
                                 const float* __restrict__ beta,
                                 const double* __restrict__ stats,
                                 unsigned short* __restrict__ Tp, float* __restrict__ csum) {
  int bid = blockIdx.x, tid = threadIdx.x;
  int n = bid / HH, h = bid - n * HH;
  __shared__ float xs[256][57];   // stride 57: transposed reads conflict-free
  const float* xb = x + (size_t)n * CHW + h * WW;
#pragma unroll
  for (int j = 0; j < 14; ++j) {
    int idx = j * 256 + tid;
    int c = idx / 14, q = idx - c * 14;
    float4 v = *(const float4*)(xb + (size_t)c * HW + q * 4);
    float* row = &xs[c][q * 4];
    row[0] = v.x; row[1] = v.y; row[2] = v.z; row[3] = v.w;
  }
  int c8 = tid & 31;
  double mu[8], sc[8], bt[8];
#pragma unroll
  for (int e = 0; e < 8; ++e) {
    int c = c8 + 32 * e;
    mu[e] = stats[c]; sc[e] = stats[C + c]; bt[e] = (double)beta[c];
  }
  __syncthreads();
  unsigned short* tb = Tp + ((size_t)(n * PH + h + 1) * PW + 1) * C;
  float* cs = csum + (size_t)(n * PH + h + 1) * PW + 1;
#pragma unroll
  for (int p = 0; p < 7; ++p) {
    int idx = p * 256 + tid;
    int w = idx >> 5;
    unsigned bits[4];
    float msum = 0.f;
#pragma unroll
    for (int e2 = 0; e2 < 4; ++e2) {
      unsigned lo, hi;
      {
        double xn = ((double)xs[c8 + 64 * e2][w] - mu[2 * e2]) * sc[2 * e2] + bt[2 * e2];
        lo = (xn > 0.0) ? 0x3F80u : 0xBF80u;
        msum += (float)fmin(fabs(xn), 1.0);
      }
      {
        double xn = ((double)xs[c8 + 64 * e2 + 32][w] - mu[2 * e2 + 1]) * sc[2 * e2 + 1] + bt[2 * e2 + 1];
        hi = (xn > 0.0) ? 0x3F80u : 0xBF80u;
        msum += (float)fmin(fabs(xn), 1.0);
      }
      bits[e2] = lo | (hi << 16);
    }
    msum += __shfl_xor(msum, 1); msum += __shfl_xor(msum, 2);
    msum += __shfl_xor(msum, 4); msum += __shfl_xor(msum, 8);
    msum += __shfl_xor(msum, 16);
    uint4 v4; v4.x = bits[0]; v4.y = bits[1]; v4.z = bits[2]; v4.w = bits[3];
    *(uint4*)(tb + (size_t)w * C + c8 * 8) = v4;
    if (c8 == 0) cs[w] = msum;
  }
}

// ------- kernel 3: tri-buffered counted-vmcnt implicit-GEMM ternary conv -------
// 512 thr / 8 waves, M=64 co x N=512 pix per block, 24 stages (kh-major, ck of 32).
// LDS: 3 buffers x [A 12,288 B | B 36,864 B] = 147,456 B -> 1 block/CU, 2 waves/SIMD.
// Unified staging: 6 GLL/thread/stage (A slots 768 + B slots 2304 = 3072 = 6x512),
// issued TWO stages ahead (stage s issues GLL(s+2) -> buf[(s+2)%3]).
// Per stage: s_waitcnt vmcnt(6)  [stage-s GLLs retired; s+1's 6 stay IN FLIGHT --
// never-zero counted wait, T3/T4] -> one s_barrier + sched_barrier(0) [pins ds_reads
// below: all waves' waits passed => buf(s) fully written] -> 3 kw-phases, each
// {8 ds_read || 2 GLL(s+2) || setprio(1) + 16 MFMA}. 144 MFMA per barrier.
// WAR on buf[(s+2)%3] (last read at stage s-1) is ordered by the leading barrier.
// A/B XOR bank swizzles + B window algebra + epilogue: verbatim from verified rounds.
__global__ __launch_bounds__(512, 2) void conv_kernel(const unsigned short* __restrict__ Wp,
    const unsigned short* __restrict__ Tp, const float* __restrict__ convb,
    const float* __restrict__ csum, const float* __restrict__ betab,
    float* __restrict__ out) {
  int bid = blockIdx.x;
  int ptg = bid >> 5, xcd = bid & 7, ct = (bid >> 3) & 3;
  int pt = ptg * 8 + xcd;                    // pixel tile (same-XCD blocks share it)
  if (pt >= 106) return;
  int tid = threadIdx.x;
  int co0 = ct * 64;

  __shared__ __align__(16) unsigned short lds[3 * 24576];   // 3 x 49,152 B

  // ---- unified staging plan: slot lin = r*512+tid; lin<768 -> A, else B.
  // A slot: [tap3][co][pseg] ; global = (co0+co)*KTOT + tap3*256 + lseg*8 (+kh*768+ck*32)
  // B slot: [brow][bseg]     ; global = q(kh,brow)*C + lseg*8 (+ck*32), q clamped
  // LDS dest (both): buf + lin*8 shorts  (A region first, B region at +6144 shorts)
  int ofs[6][3];
  const unsigned short* base1 = Wp;   // per-thread base for r=1 (wave-uniform split)
#pragma unroll
  for (int r = 0; r < 6; ++r) {
    int lin = r * 512 + tid;
    if (lin < 768) {
      int co = (lin >> 2) & 63, tap3 = lin >> 8, pseg = lin & 3;
      int lseg = pseg ^ ((co >> 1) & 3);
      int ab = (co0 + co) * KTOT + tap3 * 256 + lseg * 8;
#pragma unroll
      for (int kh = 0; kh < 3; ++kh) ofs[r][kh] = ab + kh * 768;
    } else {
      int lb = lin - 768;
      int brow = lb >> 2, bseg = lb & 3;
      int lseg = bseg ^ ((brow >> 1) & 3);
#pragma unroll
      for (int kh = 0; kh < 3; ++kh) {
        int q = pt * 512 + (kh - 1) * 58 - 32 + brow;
        q = q < 0 ? 0 : (q >= NPIXP ? NPIXP - 1 : q);  // clamped rows feed skipped outputs
        ofs[r][kh] = q * C + lseg * 8;
      }
      if (r == 1) base1 = Tp;
    }
  }

  int lane = tid & 63, wid = tid >> 6;
  int quad = lane >> 4, row16 = lane & 15;
  int aFoff = row16 * 32 + (quad ^ ((row16 >> 1) & 3)) * 8;  // + kw*2048 + mi*512
  int pixb = wid * 64 + row16;         // staged B row = pixb + ni*16 + kw + 31

  f32x4 acc[4][4];
#pragma unroll
  for (int mi = 0; mi < 4; ++mi)
#pragma unroll
    for (int ni = 0; ni < 4; ++ni)
      acc[mi][ni] = (f32x4){0.f, 0.f, 0.f, 0.f};

  // prologue: GLL(stage 0: kh0,ck0) -> buf0 ; GLL(stage 1: kh0,ck1) -> buf1
  {
    unsigned short* d0 = lds + tid * 8;
    GLL(Wp    + ofs[0][0],      d0);
    GLL(base1 + ofs[1][0],      d0 + 512 * 8);
#pragma unroll
    for (int r = 2; r < 6; ++r) GLL(Tp + ofs[r][0], d0 + r * 512 * 8);
    unsigned short* d1 = lds + 24576 + tid * 8;
    GLL(Wp    + ofs[0][0] + 32, d1);
    GLL(base1 + ofs[1][0] + 32, d1 + 512 * 8);
#pragma unroll
    for (int r = 2; r < 6; ++r) GLL(Tp + ofs[r][0] + 32, d1 + r * 512 * 8);
  }

  for (int s = 0; s < 24; ++s) {
    const unsigned short* buf = lds + (s % 3) * 24576;
    unsigned short* pbuf = lds + ((s + 2) % 3) * 24576 + tid * 8;
    int s2 = s + 2;
    int kh2 = s2 >> 3, cof2 = (s2 & 7) * 32;
    bool pref = s2 < 24;
    // counted wait: stage-s GLLs retired, stage-(s+1)'s 6 remain in flight
    if (s < 23) asm volatile("s_waitcnt vmcnt(6)" ::: "memory");
    else        asm volatile("s_waitcnt vmcnt(0)" ::: "memory");
    __builtin_amdgcn_s_barrier();          // all waves' GLL(s) landed; buf(s) ready
    __builtin_amdgcn_sched_barrier(0);     // pin ds_reads below the barrier
    const unsigned short* aF = buf + aFoff;
    const unsigned short* bB = buf + 6144;
#pragma unroll
    for (int kw = 0; kw < 3; ++kw) {
      if (pref) {
        if (kw == 0) {
          GLL(Wp    + ofs[0][kh2] + cof2, pbuf);
          GLL(base1 + ofs[1][kh2] + cof2, pbuf + 512 * 8);
        } else {
          GLL(Tp + ofs[2 * kw][kh2] + cof2,     pbuf + (2 * kw) * 512 * 8);
          GLL(Tp + ofs[2 * kw + 1][kh2] + cof2, pbuf + (2 * kw + 1) * 512 * 8);
        }
      }
      bf16x8 a[4], b[4];
#pragma unroll
      for (int mi = 0; mi < 4; ++mi)
        a[mi] = *(const bf16x8*)(aF + kw * 2048 + mi * 512);
#pragma unroll
      for (int ni = 0; ni < 4; ++ni) {
        int pix = pixb + ni * 16 + kw + 31;
        b[ni] = *(const bf16x8*)(bB + pix * 32 + ((quad ^ ((pix >> 1) & 3)) * 8));
      }
      __builtin_amdgcn_s_setprio(1);
#pragma unroll
      for (int mi = 0; mi < 4; ++mi)
#pragma unroll
        for (int ni = 0; ni < 4; ++ni)
          acc[mi][ni] = __builtin_amdgcn_mfma_f32_16x16x32_bf16(a[mi], b[ni], acc[mi][ni], 0, 0, 0);
      __builtin_amdgcn_s_setprio(0);
    }
  }

  // epilogue: out = (acc + conv_b) * beta_map(inline) ; skip padded-border outputs
  float bb = betab[0];
#pragma unroll
  for (int ni = 0; ni < 4; ++ni) {
    int pp = pt * 512 + wid * 64 + ni * 16 + row16;
    if (pp >= NPIXP) continue;
    int n = pp / PPI; int r2 = pp - n * PPI;
    int ph = r2 / PW;  int pw = r2 - ph * PW;
    if (ph < 1 || ph > 56 || pw < 1 || pw > 56) continue;
    const float* cp = csum + (size_t)(n * PH + ph - 1) * PW + (pw - 1);
    float s9 = 0.f;
#pragma unroll
    for (int i = 0; i < 3; ++i)
#pragma unroll
      for (int j = 0; j < 3; ++j) s9 += cp[i * PW + j];
    int rows = 3 - (ph == 1) - (ph == 56);
    int cols = 3 - (pw == 1) - (pw == 56);
    float bm = (s9 + bb) / (256.0f * (float)(rows * cols) + bb);
    int pix = (ph - 1) * WW + (pw - 1);
    float* ob = out + (size_t)n * CHW + pix;
#pragma unroll
    for (int mi = 0; mi < 4; ++mi) {
      int co = co0 + mi * 16 + quad * 4;
#pragma unroll
      for (int rg = 0; rg < 4; ++rg) {
        ob[(size_t)(co + rg) * HW] = (acc[mi][ni][rg] + convb[co + rg]) * bm;
      }
    }
  }
}

extern "C" void kernel_launch(void* const* d_in, const int* in_sizes, int n_in,
                              void* d_out, int out_size, void* d_ws, size_t ws_size,
                              hipStream_t stream) {
  const float* x     = (const float*)d_in[0];
  const float* gamma = (const float*)d_in[1];
  const float* beta  = (const float*)d_in[2];
  const float* convw = (const float*)d_in[3];
  const float* convb = (const float*)d_in[4];
  const float* betab = (const float*)d_in[5];
  float* out = (float*)d_out;

  char* ws = (char*)d_ws;
  unsigned short* Tp   = (unsigned short*)(ws);                 // 16*58*58*256*2 = 27,557,888
  unsigned short* Wp   = (unsigned short*)(ws + 27557888);      // 256*2304*2     =  1,179,648
  float*          csum = (float*)(ws + 28737536);               // 16*58*58*4     =    215,296
  double*         stats= (double*)(ws + 29153536);              // 512*8          =      4,096

  prep_stats_kernel<<<487, 1024, 0, stream>>>(x, gamma, convw, stats, Wp, Tp, csum);
  ternarize_kernel<<<896, 256, 0, stream>>>(x, beta, stats, Tp, csum);
  conv_kernel<<<448, 512, 0, stream>>>(Wp, Tp, convb, csum, betab, out);
}